// Round 7
// baseline (298.583 us; speedup 1.0000x reference)
//
#include <hip/hip_runtime.h>

#define DD 64
#define BW 512            // nodes per bucket (dst >> 9)
#define NBMAX 256         // supports n_nodes <= 131072
#define CAP 8192          // LDS csr staging capacity per bucket
#define CHUNK 2048        // edges per block in hist/part

typedef unsigned short u16;
typedef u16 ushort8v __attribute__((ext_vector_type(8)));
typedef short s16x8 __attribute__((ext_vector_type(8)));
typedef float f32x4 __attribute__((ext_vector_type(4)));

__device__ __forceinline__ float bf2f(u16 u) {
    union { unsigned u32; float f; } x; x.u32 = (unsigned)u << 16; return x.f;
}
__device__ __forceinline__ u16 f2bf(float f) {
    union { float f; unsigned u; } x; x.f = f;
    unsigned r = (x.u + 0x7fffu + ((x.u >> 16) & 1u)) >> 16;   // RTNE
    return (u16)r;
}

// ---------------- weight fp32->bf16 (block 0 also zeroes bucket_cnt) ----------------
__global__ void k_cvtw(const float* __restrict__ w0, const float* __restrict__ w1,
                       const float* __restrict__ w2, const float* __restrict__ w3,
                       const float* __restrict__ w4, u16* __restrict__ wb,
                       int* __restrict__ bucket_cnt) {
    if (blockIdx.x == 0) bucket_cnt[threadIdx.x] = 0;
    int i = blockIdx.x * 256 + threadIdx.x;   // grid = 80 blocks
    int mat = i >> 12, off = i & 4095;
    const float* src = (mat == 0) ? w0 : (mat == 1) ? w1 : (mat == 2) ? w2 : (mat == 3) ? w3 : w4;
    wb[i] = f2bf(src[off]);
}

// ---------------- pass A: bucket histogram ----------------
__global__ void k_hist(const int* __restrict__ ei, int n_edges, int* __restrict__ bucket_cnt) {
    __shared__ int hist[NBMAX];
    int t = threadIdx.x;
    hist[t] = 0;
    __syncthreads();
    int c0 = blockIdx.x * CHUNK;
    int c1 = min(n_edges, c0 + CHUNK);
    for (int e = c0 + t; e < c1; e += 256)
        atomicAdd(&hist[ei[n_edges + e] >> 9], 1);
    __syncthreads();
    if (hist[t] > 0) atomicAdd(&bucket_cnt[t], hist[t]);
}

// ---------------- pass B: scan bucket totals ----------------
__global__ void k_bscan(const int* __restrict__ bucket_cnt, int* __restrict__ cursor,
                        int* __restrict__ bucket_start, int* __restrict__ row_start,
                        int nb, int n_edges, int n_nodes) {
    __shared__ int lds[256];
    int t = threadIdx.x;
    lds[t] = (t < nb) ? bucket_cnt[t] : 0;
    __syncthreads();
    for (int off = 1; off < 256; off <<= 1) {
        int x = (t >= off) ? lds[t - off] : 0;
        __syncthreads();
        if (t >= off) lds[t] += x;
        __syncthreads();
    }
    int excl = (t == 0) ? 0 : lds[t - 1];
    if (t < nb) { bucket_start[t] = excl; cursor[t] = excl; }
    if (t == 0) { bucket_start[nb] = n_edges; row_start[n_nodes] = n_edges; }
}

// ---------------- pass C: partition edges into buckets ----------------
// part[pos] = (src << 9) | (dst & 511)
__global__ void k_part(const int* __restrict__ ei, int n_edges,
                       int* __restrict__ cursor, unsigned* __restrict__ part) {
    __shared__ int hist[NBMAX];
    __shared__ int curs[NBMAX];
    int t = threadIdx.x;
    hist[t] = 0;
    __syncthreads();
    int c0 = blockIdx.x * CHUNK;
    int c1 = min(n_edges, c0 + CHUNK);
    for (int e = c0 + t; e < c1; e += 256)
        atomicAdd(&hist[ei[n_edges + e] >> 9], 1);
    __syncthreads();
    int base = 0;
    if (hist[t] > 0) base = atomicAdd(&cursor[t], hist[t]);
    curs[t] = base;
    __syncthreads();
    for (int e = c0 + t; e < c1; e += 256) {
        int dst = ei[n_edges + e];
        int src = ei[e];
        int b = dst >> 9;
        int pos = atomicAdd(&curs[b], 1);
        part[pos] = ((unsigned)src << 9) | (unsigned)(dst & 511);
    }
}

// ---------------- pass D: per-bucket row_start + csr build in LDS ----------------
__global__ __launch_bounds__(256) void k_build(const unsigned* __restrict__ part,
                        const int* __restrict__ bucket_start,
                        int* __restrict__ row_start, int* __restrict__ csr, int n_nodes) {
    __shared__ int cnt_l[BW];
    __shared__ int sc[BW];
    __shared__ unsigned csr_l[CAP];
    int t = threadIdx.x;
    int b = blockIdx.x;
    int beg = bucket_start[b], end = bucket_start[b + 1];
    int size = end - beg;

    cnt_l[t] = 0; cnt_l[256 + t] = 0;
    __syncthreads();
    for (int j = beg + t; j < end; j += 256)
        atomicAdd(&cnt_l[part[j] & 511], 1);
    __syncthreads();
    int v0 = cnt_l[t], v1 = cnt_l[256 + t];
    sc[t] = v0; sc[256 + t] = v1;
    cnt_l[t] = 0; cnt_l[256 + t] = 0;
    __syncthreads();
    for (int off = 1; off < 256; off <<= 1) {
        int a = (t >= off) ? sc[t - off] : 0;
        int c = (t >= off) ? sc[256 + t - off] : 0;
        __syncthreads();
        if (t >= off) { sc[t] += a; sc[256 + t] += c; }
        __syncthreads();
    }
    int tot0 = sc[255];
    __syncthreads();
    sc[256 + t] += tot0;
    __syncthreads();
    {
        int n0 = b * BW + t;
        if (n0 < n_nodes) row_start[n0] = beg + ((t == 0) ? 0 : sc[t - 1]);
        int n1 = b * BW + 256 + t;
        if (n1 < n_nodes) row_start[n1] = beg + sc[255 + t];
    }
    if (size <= CAP) {
        for (int j = beg + t; j < end; j += 256) {
            unsigned p = part[j];
            int dl = (int)(p & 511u);
            int pos = ((dl == 0) ? 0 : sc[dl - 1]) + atomicAdd(&cnt_l[dl], 1);
            csr_l[pos] = p >> 9;
        }
        __syncthreads();
        for (int i = t; i < size; i += 256) csr[beg + i] = (int)csr_l[i];
    } else {
        for (int j = beg + t; j < end; j += 256) {
            unsigned p = part[j];
            int dl = (int)(p & 511u);
            int pos = ((dl == 0) ? 0 : sc[dl - 1]) + atomicAdd(&cnt_l[dl], 1);
            csr[beg + pos] = (int)(p >> 9);
        }
    }
}

// ---------------- node linear via MFMA: fp32 x -> bf16 h0 ----------------
// block = 4 waves x 16 nodes; wave covers all 4 dim-tiles.
__global__ __launch_bounds__(256) void k_lin(
    const float* __restrict__ A, const u16* __restrict__ W,
    const float* __restrict__ bias, u16* __restrict__ out, int n_nodes) {
    int t = threadIdx.x;
    int lane = t & 63;
    int col = lane & 15;
    int quad = lane >> 4;
    int m0 = blockIdx.x * 64 + (t >> 6) * 16;
    int arow = m0 + col;
    if (arow > n_nodes - 1) arow = n_nodes - 1;

    f32x4 acc[4];
    #pragma unroll
    for (int nt = 0; nt < 4; ++nt) {
        float bv = bias[nt * 16 + col];
        acc[nt] = (f32x4){bv, bv, bv, bv};
    }
    #pragma unroll
    for (int ks = 0; ks < 2; ++ks) {
        int k0 = ks * 32 + quad * 8;
        const float* p = A + (size_t)arow * DD + k0;
        float4 v0 = *(const float4*)p;
        float4 v1 = *(const float4*)(p + 4);
        s16x8 a;
        a[0] = (short)f2bf(v0.x); a[1] = (short)f2bf(v0.y);
        a[2] = (short)f2bf(v0.z); a[3] = (short)f2bf(v0.w);
        a[4] = (short)f2bf(v1.x); a[5] = (short)f2bf(v1.y);
        a[6] = (short)f2bf(v1.z); a[7] = (short)f2bf(v1.w);
        #pragma unroll
        for (int nt = 0; nt < 4; ++nt) {
            s16x8 b = *(const s16x8*)(W + (nt * 16 + col) * DD + k0);
            acc[nt] = __builtin_amdgcn_mfma_f32_16x16x32_bf16(a, b, acc[nt], 0, 0, 0);
        }
    }
    int mbase = m0 + quad * 4;
    #pragma unroll
    for (int nt = 0; nt < 4; ++nt)
        #pragma unroll
        for (int i = 0; i < 4; ++i) {
            int m = mbase + i;
            if (m < n_nodes) out[(size_t)m * DD + nt * 16 + col] = f2bf(acc[nt][i]);
        }
}

// ------- fused SAGE conv: gather-mean (LDS) + MFMA gemm -------
// out = [relu]( mean(h[neigh]) @ Wl^T + bias + h @ Wr^T )
// block = 64 nodes, 4 waves; wave w gathers + computes nodes m0+16w .. +15.
__global__ __launch_bounds__(256) void k_conv(
    const u16* __restrict__ h, const int* __restrict__ row_start,
    const int* __restrict__ csr,
    const u16* __restrict__ Wl, const u16* __restrict__ Wr,
    const float* __restrict__ bias, u16* __restrict__ out,
    int n_nodes, int relu) {
    __shared__ u16 mean_l[64 * DD];   // 8 KB
    int t = threadIdx.x;
    int w = t >> 6, lane = t & 63;
    int q = lane >> 3, r = lane & 7;
    int m0 = blockIdx.x * 64;

    // phase 1: gather means for this wave's 16 nodes
    for (int i = 0; i < 16; ++i) {
        int n = m0 + w * 16 + i;
        if (n >= n_nodes) break;                 // wave-uniform
        int beg = row_start[n], end = row_start[n + 1];
        float a[8];
        #pragma unroll
        for (int kk = 0; kk < 8; ++kk) a[kk] = 0.f;
        for (int j = beg + q; j < end; j += 8) {
            int s = csr[j];
            ushort8v v = *(const ushort8v*)(h + (size_t)s * DD + r * 8);
            #pragma unroll
            for (int kk = 0; kk < 8; ++kk) a[kk] += bf2f(v[kk]);
        }
        #pragma unroll
        for (int off = 8; off < 64; off <<= 1) {
            #pragma unroll
            for (int kk = 0; kk < 8; ++kk) a[kk] += __shfl_xor(a[kk], off, 64);
        }
        int deg = end - beg;
        float inv = (deg > 0) ? 1.0f / (float)deg : 0.0f;
        if (q == 0) {
            ushort8v o;
            #pragma unroll
            for (int kk = 0; kk < 8; ++kk) o[kk] = f2bf(a[kk] * inv);
            *(ushort8v*)(mean_l + (w * 16 + i) * DD + r * 8) = o;
        }
    }
    __syncthreads();

    // phase 2: MFMA
    int col = lane & 15;
    int quad = lane >> 4;
    int arow = m0 + w * 16 + col;
    if (arow > n_nodes - 1) arow = n_nodes - 1;

    f32x4 acc[4];
    #pragma unroll
    for (int nt = 0; nt < 4; ++nt) {
        float bv = bias[nt * 16 + col];
        acc[nt] = (f32x4){bv, bv, bv, bv};
    }
    #pragma unroll
    for (int ks = 0; ks < 2; ++ks) {
        int k0 = ks * 32 + quad * 8;
        s16x8 am = *(const s16x8*)(mean_l + (w * 16 + col) * DD + k0);
        s16x8 ah = *(const s16x8*)(h + (size_t)arow * DD + k0);
        #pragma unroll
        for (int nt = 0; nt < 4; ++nt) {
            s16x8 bl = *(const s16x8*)(Wl + (nt * 16 + col) * DD + k0);
            acc[nt] = __builtin_amdgcn_mfma_f32_16x16x32_bf16(am, bl, acc[nt], 0, 0, 0);
            s16x8 br = *(const s16x8*)(Wr + (nt * 16 + col) * DD + k0);
            acc[nt] = __builtin_amdgcn_mfma_f32_16x16x32_bf16(ah, br, acc[nt], 0, 0, 0);
        }
    }
    int mbase = m0 + w * 16 + quad * 4;
    #pragma unroll
    for (int nt = 0; nt < 4; ++nt)
        #pragma unroll
        for (int i = 0; i < 4; ++i) {
            int m = mbase + i;
            if (m < n_nodes) {
                float v = acc[nt][i];
                if (relu) v = fmaxf(v, 0.f);
                out[(size_t)m * DD + nt * 16 + col] = f2bf(v);
            }
        }
}

// ---------------- preds: 4 edges per wave, ushort8 loads ----------------
// lane group of 16 per edge: g = (t>>3)&1 selects endpoint, r = t&7 dim octet
__global__ void k_pred(const u16* __restrict__ h, const int* __restrict__ eli,
                       int n_label, float* __restrict__ out) {
    int t = threadIdx.x;
    int e = blockIdx.x * 16 + (t >> 4);
    if (e >= n_label) return;
    int g = (t >> 3) & 1;
    int r = t & 7;
    int node = g ? eli[n_label + e] : eli[e];
    ushort8v v = *(const ushort8v*)(h + (size_t)node * DD + r * 8);
    float s = 0.f;
    #pragma unroll
    for (int kk = 0; kk < 8; ++kk) {
        float f = bf2f(v[kk]);
        s += f * __shfl_xor(f, 8, 64);   // pair with other endpoint, same octet
    }
    #pragma unroll
    for (int off = 1; off < 8; off <<= 1) s += __shfl_xor(s, off, 64);
    if ((t & 15) == 0) out[e] = s;
}

extern "C" void kernel_launch(void* const* d_in, const int* in_sizes, int n_in,
                              void* d_out, int out_size, void* d_ws, size_t ws_size,
                              hipStream_t stream) {
    const float* x     = (const float*)d_in[0];
    const int*   ei    = (const int*)d_in[1];
    const int*   eli   = (const int*)d_in[2];
    const float* W_lin = (const float*)d_in[3];
    const float* b_lin = (const float*)d_in[4];
    const float* Wl1   = (const float*)d_in[5];
    const float* bl1   = (const float*)d_in[6];
    const float* Wr1   = (const float*)d_in[7];
    const float* Wl2   = (const float*)d_in[8];
    const float* bl2   = (const float*)d_in[9];
    const float* Wr2   = (const float*)d_in[10];

    int n_nodes = in_sizes[0] / DD;
    int n_edges = in_sizes[1] / 2;
    int n_label = in_sizes[2] / 2;
    float* out = (float*)d_out;

    int nb = (n_nodes + BW - 1) / BW;     // buckets (196 for 100K)

    char* ws = (char*)d_ws;
    size_t hbytes = (size_t)n_nodes * DD * sizeof(u16);
    u16* hA   = (u16*)ws; ws += hbytes;
    u16* hB   = (u16*)ws; ws += hbytes;
    int* row_start    = (int*)ws; ws += (size_t)((n_nodes + 5) & ~3) * sizeof(int);
    int* bucket_cnt   = (int*)ws; ws += NBMAX * sizeof(int);
    int* bucket_start = (int*)ws; ws += (NBMAX + 4) * sizeof(int);
    int* cursor       = (int*)ws; ws += NBMAX * sizeof(int);
    u16* wb           = (u16*)ws; ws += 5 * DD * DD * sizeof(u16);
    unsigned* part    = (unsigned*)ws; ws += (size_t)n_edges * sizeof(unsigned);
    int* csr          = (int*)ws; ws += (size_t)n_edges * sizeof(int);

    int nb_chunk = (n_edges + CHUNK - 1) / CHUNK;

    // weight conversion + bucket_cnt zeroing
    k_cvtw<<<80, 256, 0, stream>>>(W_lin, Wl1, Wr1, Wl2, Wr2, wb, bucket_cnt);

    // CSR build (2-level counting sort)
    k_hist<<<nb_chunk, 256, 0, stream>>>(ei, n_edges, bucket_cnt);
    k_bscan<<<1, 256, 0, stream>>>(bucket_cnt, cursor, bucket_start, row_start, nb, n_edges, n_nodes);
    k_part<<<nb_chunk, 256, 0, stream>>>(ei, n_edges, cursor, part);
    k_build<<<nb, 256, 0, stream>>>(part, bucket_start, row_start, csr, n_nodes);

    int nb_gemm = (n_nodes + 63) / 64;
    int nb_pred = (n_label + 15) / 16;

    // layer 0: node linear
    k_lin<<<nb_gemm, 256, 0, stream>>>(x, wb, b_lin, hA, n_nodes);

    // conv1 (fused gather + gemm)
    k_conv<<<nb_gemm, 256, 0, stream>>>(hA, row_start, csr, wb + 4096, wb + 2 * 4096, bl1, hB, n_nodes, 1);

    // conv2
    k_conv<<<nb_gemm, 256, 0, stream>>>(hB, row_start, csr, wb + 3 * 4096, wb + 4 * 4096, bl2, hA, n_nodes, 0);

    // edge classifier
    k_pred<<<nb_pred, 256, 0, stream>>>(hA, eli, n_label, out);
}

// Round 8
// 250.528 us; speedup vs baseline: 1.1918x; 1.1918x over previous
//
#include <hip/hip_runtime.h>

#define DD 64
#define BW 512            // nodes per bucket (dst >> 9)
#define NBMAX 256         // supports n_nodes <= 131072
#define CAP 8192          // LDS csr staging capacity per bucket
#define CHUNK 2048        // edges per block in hist/part

typedef unsigned short u16;
typedef u16 ushort8v __attribute__((ext_vector_type(8)));
typedef short s16x8 __attribute__((ext_vector_type(8)));
typedef float f32x4 __attribute__((ext_vector_type(4)));

__device__ __forceinline__ float bf2f(u16 u) {
    union { unsigned u32; float f; } x; x.u32 = (unsigned)u << 16; return x.f;
}
__device__ __forceinline__ u16 f2bf(float f) {
    union { float f; unsigned u; } x; x.f = f;
    unsigned r = (x.u + 0x7fffu + ((x.u >> 16) & 1u)) >> 16;   // RTNE
    return (u16)r;
}

// ---------------- weight fp32->bf16 (block 0 also zeroes bucket_cnt) ----------------
__global__ void k_cvtw(const float* __restrict__ w0, const float* __restrict__ w1,
                       const float* __restrict__ w2, const float* __restrict__ w3,
                       const float* __restrict__ w4, u16* __restrict__ wb,
                       int* __restrict__ bucket_cnt) {
    if (blockIdx.x == 0) bucket_cnt[threadIdx.x] = 0;
    int i = blockIdx.x * 256 + threadIdx.x;   // grid = 80 blocks
    int mat = i >> 12, off = i & 4095;
    const float* src = (mat == 0) ? w0 : (mat == 1) ? w1 : (mat == 2) ? w2 : (mat == 3) ? w3 : w4;
    wb[i] = f2bf(src[off]);
}

// ---------------- pass A: bucket histogram ----------------
__global__ void k_hist(const int* __restrict__ ei, int n_edges, int* __restrict__ bucket_cnt) {
    __shared__ int hist[NBMAX];
    int t = threadIdx.x;
    hist[t] = 0;
    __syncthreads();
    int c0 = blockIdx.x * CHUNK;
    int c1 = min(n_edges, c0 + CHUNK);
    for (int e = c0 + t; e < c1; e += 256)
        atomicAdd(&hist[ei[n_edges + e] >> 9], 1);
    __syncthreads();
    if (hist[t] > 0) atomicAdd(&bucket_cnt[t], hist[t]);
}

// ---------------- pass B: scan bucket totals ----------------
__global__ void k_bscan(const int* __restrict__ bucket_cnt, int* __restrict__ cursor,
                        int* __restrict__ bucket_start, int* __restrict__ row_start,
                        int nb, int n_edges, int n_nodes) {
    __shared__ int lds[256];
    int t = threadIdx.x;
    lds[t] = (t < nb) ? bucket_cnt[t] : 0;
    __syncthreads();
    for (int off = 1; off < 256; off <<= 1) {
        int x = (t >= off) ? lds[t - off] : 0;
        __syncthreads();
        if (t >= off) lds[t] += x;
        __syncthreads();
    }
    int excl = (t == 0) ? 0 : lds[t - 1];
    if (t < nb) { bucket_start[t] = excl; cursor[t] = excl; }
    if (t == 0) { bucket_start[nb] = n_edges; row_start[n_nodes] = n_edges; }
}

// ---------------- pass C: partition edges into buckets ----------------
// part[pos] = (src << 9) | (dst & 511)
__global__ void k_part(const int* __restrict__ ei, int n_edges,
                       int* __restrict__ cursor, unsigned* __restrict__ part) {
    __shared__ int hist[NBMAX];
    __shared__ int curs[NBMAX];
    int t = threadIdx.x;
    hist[t] = 0;
    __syncthreads();
    int c0 = blockIdx.x * CHUNK;
    int c1 = min(n_edges, c0 + CHUNK);
    for (int e = c0 + t; e < c1; e += 256)
        atomicAdd(&hist[ei[n_edges + e] >> 9], 1);
    __syncthreads();
    int base = 0;
    if (hist[t] > 0) base = atomicAdd(&cursor[t], hist[t]);
    curs[t] = base;
    __syncthreads();
    for (int e = c0 + t; e < c1; e += 256) {
        int dst = ei[n_edges + e];
        int src = ei[e];
        int b = dst >> 9;
        int pos = atomicAdd(&curs[b], 1);
        part[pos] = ((unsigned)src << 9) | (unsigned)(dst & 511);
    }
}

// ---------------- pass D: per-bucket row_start + csr build in LDS ----------------
__global__ __launch_bounds__(256) void k_build(const unsigned* __restrict__ part,
                        const int* __restrict__ bucket_start,
                        int* __restrict__ row_start, int* __restrict__ csr, int n_nodes) {
    __shared__ int cnt_l[BW];
    __shared__ int sc[BW];
    __shared__ unsigned csr_l[CAP];
    int t = threadIdx.x;
    int b = blockIdx.x;
    int beg = bucket_start[b], end = bucket_start[b + 1];
    int size = end - beg;

    cnt_l[t] = 0; cnt_l[256 + t] = 0;
    __syncthreads();
    for (int j = beg + t; j < end; j += 256)
        atomicAdd(&cnt_l[part[j] & 511], 1);
    __syncthreads();
    int v0 = cnt_l[t], v1 = cnt_l[256 + t];
    sc[t] = v0; sc[256 + t] = v1;
    cnt_l[t] = 0; cnt_l[256 + t] = 0;
    __syncthreads();
    for (int off = 1; off < 256; off <<= 1) {
        int a = (t >= off) ? sc[t - off] : 0;
        int c = (t >= off) ? sc[256 + t - off] : 0;
        __syncthreads();
        if (t >= off) { sc[t] += a; sc[256 + t] += c; }
        __syncthreads();
    }
    int tot0 = sc[255];
    __syncthreads();
    sc[256 + t] += tot0;
    __syncthreads();
    {
        int n0 = b * BW + t;
        if (n0 < n_nodes) row_start[n0] = beg + ((t == 0) ? 0 : sc[t - 1]);
        int n1 = b * BW + 256 + t;
        if (n1 < n_nodes) row_start[n1] = beg + sc[255 + t];
    }
    if (size <= CAP) {
        for (int j = beg + t; j < end; j += 256) {
            unsigned p = part[j];
            int dl = (int)(p & 511u);
            int pos = ((dl == 0) ? 0 : sc[dl - 1]) + atomicAdd(&cnt_l[dl], 1);
            csr_l[pos] = p >> 9;
        }
        __syncthreads();
        for (int i = t; i < size; i += 256) csr[beg + i] = (int)csr_l[i];
    } else {
        for (int j = beg + t; j < end; j += 256) {
            unsigned p = part[j];
            int dl = (int)(p & 511u);
            int pos = ((dl == 0) ? 0 : sc[dl - 1]) + atomicAdd(&cnt_l[dl], 1);
            csr[beg + pos] = (int)(p >> 9);
        }
    }
}

// ---------------- node linear via MFMA: fp32 x -> bf16 h0 ----------------
__global__ __launch_bounds__(256) void k_lin(
    const float* __restrict__ A, const u16* __restrict__ W,
    const float* __restrict__ bias, u16* __restrict__ out, int n_nodes) {
    int t = threadIdx.x;
    int lane = t & 63;
    int col = lane & 15;
    int quad = lane >> 4;
    int m0 = blockIdx.x * 64 + (t >> 6) * 16;
    int arow = m0 + col;
    if (arow > n_nodes - 1) arow = n_nodes - 1;

    f32x4 acc[4];
    #pragma unroll
    for (int nt = 0; nt < 4; ++nt) {
        float bv = bias[nt * 16 + col];
        acc[nt] = (f32x4){bv, bv, bv, bv};
    }
    #pragma unroll
    for (int ks = 0; ks < 2; ++ks) {
        int k0 = ks * 32 + quad * 8;
        const float* p = A + (size_t)arow * DD + k0;
        float4 v0 = *(const float4*)p;
        float4 v1 = *(const float4*)(p + 4);
        s16x8 a;
        a[0] = (short)f2bf(v0.x); a[1] = (short)f2bf(v0.y);
        a[2] = (short)f2bf(v0.z); a[3] = (short)f2bf(v0.w);
        a[4] = (short)f2bf(v1.x); a[5] = (short)f2bf(v1.y);
        a[6] = (short)f2bf(v1.z); a[7] = (short)f2bf(v1.w);
        #pragma unroll
        for (int nt = 0; nt < 4; ++nt) {
            s16x8 b = *(const s16x8*)(W + (nt * 16 + col) * DD + k0);
            acc[nt] = __builtin_amdgcn_mfma_f32_16x16x32_bf16(a, b, acc[nt], 0, 0, 0);
        }
    }
    int mbase = m0 + quad * 4;
    #pragma unroll
    for (int nt = 0; nt < 4; ++nt)
        #pragma unroll
        for (int i = 0; i < 4; ++i) {
            int m = mbase + i;
            if (m < n_nodes) out[(size_t)m * DD + nt * 16 + col] = f2bf(acc[nt][i]);
        }
}

// ------- fused SAGE conv: shuffle-free gather-mean (LDS) + MFMA gemm -------
// phase 1: wave processes 8 nodes in parallel (lane = node-slot*8 + octet),
//          in-lane accumulation over neighbors, no cross-lane reduce.
// phase 2: 16x16x32 MFMA, A1 = mean from LDS, A2 = h from global.
__global__ __launch_bounds__(256) void k_conv(
    const u16* __restrict__ h, const int* __restrict__ row_start,
    const int* __restrict__ csr,
    const u16* __restrict__ Wl, const u16* __restrict__ Wr,
    const float* __restrict__ bias, u16* __restrict__ out,
    int n_nodes, int relu) {
    __shared__ u16 mean_l[64 * DD];   // 8 KB
    int t = threadIdx.x;
    int w = t >> 6, lane = t & 63;
    int nn = lane >> 3;   // node slot 0..7
    int r = lane & 7;     // dim octet
    int m0 = blockIdx.x * 64;

    #pragma unroll
    for (int pass = 0; pass < 2; ++pass) {
        int li = w * 16 + pass * 8 + nn;     // local node index 0..63
        int n = m0 + li;
        int beg = 0, end = 0;
        if (n < n_nodes) { beg = row_start[n]; end = row_start[n + 1]; }
        float a[8];
        #pragma unroll
        for (int kk = 0; kk < 8; ++kk) a[kk] = 0.f;
        int j = beg;
        for (; j + 1 < end; j += 2) {
            int s0 = csr[j], s1 = csr[j + 1];
            ushort8v v0 = *(const ushort8v*)(h + (size_t)s0 * DD + r * 8);
            ushort8v v1 = *(const ushort8v*)(h + (size_t)s1 * DD + r * 8);
            #pragma unroll
            for (int kk = 0; kk < 8; ++kk) a[kk] += bf2f(v0[kk]) + bf2f(v1[kk]);
        }
        if (j < end) {
            int s0 = csr[j];
            ushort8v v0 = *(const ushort8v*)(h + (size_t)s0 * DD + r * 8);
            #pragma unroll
            for (int kk = 0; kk < 8; ++kk) a[kk] += bf2f(v0[kk]);
        }
        int deg = end - beg;
        float inv = (deg > 0) ? 1.0f / (float)deg : 0.0f;
        ushort8v o;
        #pragma unroll
        for (int kk = 0; kk < 8; ++kk) o[kk] = f2bf(a[kk] * inv);
        *(ushort8v*)(mean_l + li * DD + r * 8) = o;   // OOB nodes write 0
    }
    __syncthreads();

    // phase 2: MFMA
    int col = lane & 15;
    int quad = lane >> 4;
    int arow = m0 + w * 16 + col;
    if (arow > n_nodes - 1) arow = n_nodes - 1;

    f32x4 acc[4];
    #pragma unroll
    for (int nt = 0; nt < 4; ++nt) {
        float bv = bias[nt * 16 + col];
        acc[nt] = (f32x4){bv, bv, bv, bv};
    }
    #pragma unroll
    for (int ks = 0; ks < 2; ++ks) {
        int k0 = ks * 32 + quad * 8;
        s16x8 am = *(const s16x8*)(mean_l + (w * 16 + col) * DD + k0);
        s16x8 ah = *(const s16x8*)(h + (size_t)arow * DD + k0);
        #pragma unroll
        for (int nt = 0; nt < 4; ++nt) {
            s16x8 bl = *(const s16x8*)(Wl + (nt * 16 + col) * DD + k0);
            acc[nt] = __builtin_amdgcn_mfma_f32_16x16x32_bf16(am, bl, acc[nt], 0, 0, 0);
            s16x8 br = *(const s16x8*)(Wr + (nt * 16 + col) * DD + k0);
            acc[nt] = __builtin_amdgcn_mfma_f32_16x16x32_bf16(ah, br, acc[nt], 0, 0, 0);
        }
    }
    int mbase = m0 + w * 16 + quad * 4;
    #pragma unroll
    for (int nt = 0; nt < 4; ++nt)
        #pragma unroll
        for (int i = 0; i < 4; ++i) {
            int m = mbase + i;
            if (m < n_nodes) {
                float v = acc[nt][i];
                if (relu) v = fmaxf(v, 0.f);
                out[(size_t)m * DD + nt * 16 + col] = f2bf(v);
            }
        }
}

// ---------------- preds: 4 edges per wave, ushort8 loads ----------------
__global__ void k_pred(const u16* __restrict__ h, const int* __restrict__ eli,
                       int n_label, float* __restrict__ out) {
    int t = threadIdx.x;
    int e = blockIdx.x * 16 + (t >> 4);
    if (e >= n_label) return;
    int g = (t >> 3) & 1;
    int r = t & 7;
    int node = g ? eli[n_label + e] : eli[e];
    ushort8v v = *(const ushort8v*)(h + (size_t)node * DD + r * 8);
    float s = 0.f;
    #pragma unroll
    for (int kk = 0; kk < 8; ++kk) {
        float f = bf2f(v[kk]);
        s += f * __shfl_xor(f, 8, 64);   // pair with other endpoint, same octet
    }
    #pragma unroll
    for (int off = 1; off < 8; off <<= 1) s += __shfl_xor(s, off, 64);
    if ((t & 15) == 0) out[e] = s;
}

extern "C" void kernel_launch(void* const* d_in, const int* in_sizes, int n_in,
                              void* d_out, int out_size, void* d_ws, size_t ws_size,
                              hipStream_t stream) {
    const float* x     = (const float*)d_in[0];
    const int*   ei    = (const int*)d_in[1];
    const int*   eli   = (const int*)d_in[2];
    const float* W_lin = (const float*)d_in[3];
    const float* b_lin = (const float*)d_in[4];
    const float* Wl1   = (const float*)d_in[5];
    const float* bl1   = (const float*)d_in[6];
    const float* Wr1   = (const float*)d_in[7];
    const float* Wl2   = (const float*)d_in[8];
    const float* bl2   = (const float*)d_in[9];
    const float* Wr2   = (const float*)d_in[10];

    int n_nodes = in_sizes[0] / DD;
    int n_edges = in_sizes[1] / 2;
    int n_label = in_sizes[2] / 2;
    float* out = (float*)d_out;

    int nb = (n_nodes + BW - 1) / BW;     // buckets (196 for 100K)

    char* ws = (char*)d_ws;
    size_t hbytes = (size_t)n_nodes * DD * sizeof(u16);
    u16* hA   = (u16*)ws; ws += hbytes;
    u16* hB   = (u16*)ws; ws += hbytes;
    int* row_start    = (int*)ws; ws += (size_t)((n_nodes + 5) & ~3) * sizeof(int);
    int* bucket_cnt   = (int*)ws; ws += NBMAX * sizeof(int);
    int* bucket_start = (int*)ws; ws += (NBMAX + 4) * sizeof(int);
    int* cursor       = (int*)ws; ws += NBMAX * sizeof(int);
    u16* wb           = (u16*)ws; ws += 5 * DD * DD * sizeof(u16);
    unsigned* part    = (unsigned*)ws; ws += (size_t)n_edges * sizeof(unsigned);
    int* csr          = (int*)ws; ws += (size_t)n_edges * sizeof(int);

    int nb_chunk = (n_edges + CHUNK - 1) / CHUNK;

    // weight conversion + bucket_cnt zeroing
    k_cvtw<<<80, 256, 0, stream>>>(W_lin, Wl1, Wr1, Wl2, Wr2, wb, bucket_cnt);

    // CSR build (2-level counting sort)
    k_hist<<<nb_chunk, 256, 0, stream>>>(ei, n_edges, bucket_cnt);
    k_bscan<<<1, 256, 0, stream>>>(bucket_cnt, cursor, bucket_start, row_start, nb, n_edges, n_nodes);
    k_part<<<nb_chunk, 256, 0, stream>>>(ei, n_edges, cursor, part);
    k_build<<<nb, 256, 0, stream>>>(part, bucket_start, row_start, csr, n_nodes);

    int nb_gemm = (n_nodes + 63) / 64;
    int nb_pred = (n_label + 15) / 16;

    // layer 0: node linear
    k_lin<<<nb_gemm, 256, 0, stream>>>(x, wb, b_lin, hA, n_nodes);

    // conv1 (fused gather + gemm)
    k_conv<<<nb_gemm, 256, 0, stream>>>(hA, row_start, csr, wb + 4096, wb + 2 * 4096, bl1, hB, n_nodes, 1);

    // conv2
    k_conv<<<nb_gemm, 256, 0, stream>>>(hB, row_start, csr, wb + 3 * 4096, wb + 4 * 4096, bl2, hA, n_nodes, 0);

    // edge classifier
    k_pred<<<nb_pred, 256, 0, stream>>>(hA, eli, n_label, out);
}